// Round 11
// baseline (444.707 us; speedup 1.0000x reference)
//
#include <hip/hip_runtime.h>
#include <stdint.h>

#pragma clang fp contract(off)

#define BB 16
#define NN 25200
#define ROW 85
#define NCLS 80
#define TK 2048
#define SORTN 4096
#define NBIN 4096
#define MAXDET 1000
#define CONF 0.25f
#define IOUT 0.45f
#define SROWS 64
#define STH 0x3E800000u
#define MCAP 256
#define SCB ((NN + 1023) / 1024)   // 25 scatter blocks per batch

typedef float fvec4 __attribute__((ext_vector_type(4)));

#define AS1 __attribute__((address_space(1)))
#define AS3 __attribute__((address_space(3)))

// ---------------- K1: coalesced LDS staging + scores + argmax + global histogram ----------------
__global__ __launch_bounds__(128) void score_kernel(const float* __restrict__ pred,
                                                    float* __restrict__ scores,
                                                    uint8_t* __restrict__ cls,
                                                    unsigned int* __restrict__ hist) {
  __shared__ __align__(16) float srow[SROWS * ROW];  // 21760 B
  const int tile = blockIdx.x;
  const int b = blockIdx.y;
  const int tid = threadIdx.x;
  const int lane = tid & 63;
  const int row0 = tile * SROWS;
  int nrows = NN - row0;
  if (nrows > SROWS) nrows = SROWS;
  const char* gsrc = (const char*)(pred + ((size_t)b * NN + row0) * ROW);
  const int nbytes = nrows * ROW * 4;
  for (int off = tid * 16; off < nbytes; off += 128 * 16) {
    __builtin_amdgcn_global_load_lds((AS1 void*)(gsrc + off),
                                     (AS3 void*)((char*)srow + (off - lane * 16)),
                                     16, 0, 0);
  }
  __builtin_amdgcn_s_waitcnt(0);
  __syncthreads();
  if (tid < nrows) {
    const int n = row0 + tid;
    const float* r = srow + tid * ROW;   // stride 85 dwords -> 2-way bank alias (free)
    float obj = r[4];
    float best = r[5];
    int bid = 0;
#pragma unroll
    for (int c = 1; c < NCLS; ++c) {
      float p = r[5 + c];
      if (p > best) { best = p; bid = c; }   // strict > keeps first max (tie rule)
    }
    float score = obj * best;
    bool valid = (obj > CONF) && (score > CONF);
    float sout = valid ? score : 0.0f;
    scores[(size_t)b * NN + n] = sout;
    cls[(size_t)b * NN + n] = (uint8_t)bid;
    if (valid) {
      unsigned int u = __float_as_uint(sout);        // in (0x3E800000, 0x3F800000)
      unsigned int bin = (u - (STH + 1u)) >> 12;
      if (bin > NBIN - 1) bin = NBIN - 1;
      atomicAdd(&hist[(size_t)b * NBIN + bin], 1u);
    }
  }
}

// ---- 1024-thread per-block suffix scan over descending bins (R6 phase-2, proven) ----
__device__ __forceinline__ void suffix_scan_1024(const unsigned int* __restrict__ h,
                                                 unsigned int* soff, int* swsum,
                                                 int* sPP, int* sTT,
                                                 int t, int w, int lane) {
  int loc[4];
  int ssum = 0;
#pragma unroll
  for (int k = 0; k < 4; ++k) {
    loc[k] = (int)h[NBIN - 1 - (4 * t + k)];
    ssum += loc[k];
  }
  int v = ssum;
  for (int o = 1; o < 64; o <<= 1) { int uu = __shfl_up(v, o); if (lane >= o) v += uu; }
  if (lane == 63) swsum[w] = v;
  if (t == 0) *sPP = -1;
  __syncthreads();
  if (w == 0) {
    int x = (lane < 16) ? swsum[lane] : 0;
    for (int o = 1; o < 16; o <<= 1) { int uu = __shfl_up(x, o); if (lane >= o) x += uu; }
    if (lane < 16) swsum[lane] = x;   // inclusive wave sums
  }
  __syncthreads();
  const int total = swsum[15];
  int run = (w ? swsum[w - 1] : 0) + (v - ssum);
#pragma unroll
  for (int k = 0; k < 4; ++k) {
    int bin = NBIN - 1 - (4 * t + k);
    soff[bin] = (unsigned int)run;
    if (run < TK && run + loc[k] >= TK) { *sPP = bin; *sTT = run + loc[k]; }  // unique bin
    run += loc[k];
  }
  __syncthreads();
  if (t == 0 && *sPP < 0) { *sPP = 0; *sTT = total; }  // total < TK (never with this data)
  __syncthreads();
}

// ---------------- K2: scatter + (last block per batch) rank-by-count emit ----------------
// CUB-style last-block-done: producers store gskey, __threadfence (device scope), block
// barrier, t0 atomicAdd(done[b]); the 25th block re-fences and emits using its own LDS soff.
__global__ __launch_bounds__(1024) void scatter_emit_kernel(const float* __restrict__ pred,
                                                            const uint8_t* __restrict__ cls,
                                                            const float* __restrict__ scores,
                                                            const unsigned int* __restrict__ hist,
                                                            unsigned int* __restrict__ gcnt,
                                                            unsigned int* __restrict__ done,
                                                            unsigned long long* __restrict__ gskey,
                                                            float* __restrict__ gtops,
                                                            fvec4* __restrict__ gbox,
                                                            int* __restrict__ gcls,
                                                            int* __restrict__ keep) {
  const int b = blockIdx.y;
  const int t = threadIdx.x;
  const int w = t >> 6, lane = t & 63;
  __shared__ unsigned int soff[NBIN];   // 16 KB (base offsets; NOT advanced)
  __shared__ int swsum[16];
  __shared__ int sP, sT;
  __shared__ int sLast;
  const unsigned int* h = hist + (size_t)b * NBIN;
  suffix_scan_1024(h, soff, swsum, &sP, &sT, t, w, lane);
  const int P = sP;

  // ---- scatter this block's slice ----
  const int n = blockIdx.x * 1024 + t;
  if (n < NN) {
    unsigned int u = __float_as_uint(scores[(size_t)b * NN + n]);
    if (u > STH) {
      unsigned int bin = (u - (STH + 1u)) >> 12;
      if (bin > NBIN - 1) bin = NBIN - 1;
      if ((int)bin >= P) {
        unsigned int pos = soff[bin] + atomicAdd(&gcnt[(size_t)b * NBIN + bin], 1u);
        if (pos < SORTN)
          gskey[(size_t)b * SORTN + pos] = ((unsigned long long)u << 32) | (unsigned int)(~n);
      }
    }
  }

  // ---- release: make stores visible, then count this block done ----
  __threadfence();
  __syncthreads();
  if (t == 0) sLast = (atomicAdd(&done[b], 1u) == SCB - 1) ? 1 : 0;
  __syncthreads();
  if (!sLast) return;
  __threadfence();   // acquire: observe all batches' scatter stores

  // ---- emit body (R10-proven), run by the last block with its own soff/sT ----
  const int tot = sT;
  const int used = tot < SORTN ? tot : SORTN;
  const int npos = tot < TK ? tot : TK;
  for (int ip = npos + t; ip < TK; ip += 1024) {   // pad [npos, TK)
    gtops[(size_t)b * TK + ip] = 0.0f;
    gcls[(size_t)b * TK + ip] = 0xFFFF;
    keep[(size_t)b * TK + ip] = 0;
    fvec4 z; z[0] = 0.f; z[1] = 0.f; z[2] = 0.f; z[3] = 0.f;
    gbox[(size_t)b * TK + ip] = z;
  }
  for (int pp = t; pp < used; pp += 1024) {
    unsigned long long k = gskey[(size_t)b * SORTN + pp];
    unsigned int u = (unsigned int)(k >> 32);
    unsigned int bin = (u - (STH + 1u)) >> 12;
    if (bin > NBIN - 1) bin = NBIN - 1;
    int base = (int)soff[bin];
    int cnt = (int)h[bin];               // scattered count == hist count (tot <= SORTN)
    if (base + cnt > used) cnt = used - base;   // safety
    const unsigned long long* seg = gskey + (size_t)b * SORTN + base;
    int rank = 0;
    for (int j = 0; j < cnt; ++j) rank += (seg[j] > k) ? 1 : 0;   // L2-resident, avg ~6
    int q = base + rank;                 // bijection over the segment (keys unique)
    if (q < npos) {
      int idx = (int)(~(unsigned int)k);
      gtops[(size_t)b * TK + q] = __uint_as_float(u);
      gcls[(size_t)b * TK + q] = (int)cls[(size_t)b * NN + idx];
      const float* rowp = pred + ((size_t)b * NN + idx) * ROW;
      float cx = rowp[0], cy = rowp[1], w2 = rowp[2], h2 = rowp[3];
      float hw = w2 * 0.5f, hh = h2 * 0.5f;
      fvec4 bb4;
      bb4[0] = cx - hw; bb4[1] = cy - hh; bb4[2] = cx + hw; bb4[3] = cy + hh;
      gbox[(size_t)b * TK + q] = bb4;
    }
  }
}

// ---------------- K3: per-(batch,class) NMS + (last class-block per batch) output ----------------
__global__ __launch_bounds__(64) void nms_out_kernel(const float* __restrict__ gtops,
                                                     const fvec4* __restrict__ gbox,
                                                     const int* __restrict__ gcls,
                                                     unsigned int* __restrict__ done2,
                                                     int* __restrict__ keep,
                                                     float* __restrict__ out) {
  const int c = blockIdx.x;
  const int b = blockIdx.y;
  const int lane = threadIdx.x;
  __shared__ unsigned short spos[TK];                      // member -> global slot (4 KB)
  __shared__ float mx1[MCAP], my1[MCAP], mx2[MCAP], my2[MCAP];  // 4 KB
  __shared__ unsigned char skp[TK];                        // member keep flags (2 KB)
  __shared__ int sLast;

  int m = 0;
#pragma unroll 4
  for (int base = 0; base < TK; base += 64) {
    int j = base + lane;
    bool match = (gcls[(size_t)b * TK + j] == c);
    unsigned long long bal = __ballot(match);
    int mp = m + __popcll(bal & ((1ull << lane) - 1ull));
    if (match) {
      spos[mp] = (unsigned short)j;
      skp[mp] = (gtops[(size_t)b * TK + j] > 0.0f) ? 1 : 0;
      if (mp < MCAP) {
        fvec4 bx = gbox[(size_t)b * TK + j];
        mx1[mp] = bx[0]; my1[mp] = bx[1]; mx2[mp] = bx[2]; my2[mp] = bx[3];
      }
    }
    m += (int)__popcll(bal);
  }
  __syncthreads();

  // chunk-0 member box in registers (lane < 64 <= MCAP always staged)
  float b0x1 = 0.f, b0y1 = 0.f, b0x2 = 0.f, b0y2 = 0.f;
  if (lane < m) { b0x1 = mx1[lane]; b0y1 = my1[lane]; b0x2 = mx2[lane]; b0y2 = my2[lane]; }
  __syncthreads();

  for (int i = 0; i < m; ++i) {
    if (!skp[i]) continue;            // uniform broadcast read
    float ax1, ay1, ax2, ay2;
    if (i < 64) {
      ax1 = __shfl(b0x1, i); ay1 = __shfl(b0y1, i);
      ax2 = __shfl(b0x2, i); ay2 = __shfl(b0y2, i);
    } else if (i < MCAP) {
      ax1 = mx1[i]; ay1 = my1[i]; ax2 = mx2[i]; ay2 = my2[i];
    } else {                          // never in practice
      fvec4 bx = gbox[(size_t)b * TK + spos[i]];
      ax1 = bx[0]; ay1 = bx[1]; ax2 = bx[2]; ay2 = bx[3];
    }
    float aarea = (ax2 - ax1) * (ay2 - ay1);
    for (int q = 0; q * 64 < m; ++q) {
      int j = q * 64 + lane;          // each lane owns j == lane (mod 64): exclusive skp writes
      if (j > i && j < m && skp[j]) {
        float jx1, jy1, jx2, jy2;
        if (q == 0) { jx1 = b0x1; jy1 = b0y1; jx2 = b0x2; jy2 = b0y2; }
        else if (j < MCAP) { jx1 = mx1[j]; jy1 = my1[j]; jx2 = mx2[j]; jy2 = my2[j]; }
        else { fvec4 bx = gbox[(size_t)b * TK + spos[j]];
               jx1 = bx[0]; jy1 = bx[1]; jx2 = bx[2]; jy2 = bx[3]; }
        float ltx = fmaxf(ax1, jx1), lty = fmaxf(ay1, jy1);
        float rbx = fminf(ax2, jx2), rby = fminf(ay2, jy2);
        float iw = fmaxf(rbx - ltx, 0.0f);
        float ih = fmaxf(rby - lty, 0.0f);
        float inter = iw * ih;
        float barea = (jx2 - jx1) * (jy2 - jy1);
        float iou = inter / (aarea + barea - inter + 1e-7f);
        if (iou > IOUT) skp[j] = 0;
      }
    }
  }
  __syncthreads();

  for (int i = lane; i < m; i += 64) {
    keep[(size_t)b * TK + spos[i]] = skp[i];
  }

  // ---- release keep, count class-block done ----
  __threadfence();
  __syncthreads();
  if (lane == 0) sLast = (atomicAdd(&done2[b], 1u) == NCLS - 1) ? 1 : 0;
  __syncthreads();
  if (!sLast) return;
  __threadfence();   // acquire: observe all classes' keep writes

  // ---- output compaction, single wave (CH = 32, static unroll) ----
  const int CH = TK / 64;   // 32
  int base2 = lane * CH;
  int kp[CH];
  int cnt = 0;
#pragma unroll
  for (int k = 0; k < CH; ++k) {
    kp[k] = keep[(size_t)b * TK + base2 + k];   // pad slots hold 0 (written by emit)
    cnt += kp[k];
  }
  int v = cnt;
  for (int o = 1; o < 64; o <<= 1) { int u = __shfl_up(v, o); if (lane >= o) v += u; }
  int K = __shfl(v, 63);
  int r = v - cnt;
#pragma unroll
  for (int k = 0; k < CH; ++k) {
    if (kp[k]) {
      if (r < MAXDET) {
        int j = base2 + k;
        float* o = out + ((size_t)b * MAXDET + r) * 6;
        fvec4 bx = gbox[(size_t)b * TK + j];
        o[0] = bx[0]; o[1] = bx[1]; o[2] = bx[2]; o[3] = bx[3];
        o[4] = gtops[(size_t)b * TK + j];
        o[5] = (float)gcls[(size_t)b * TK + j];
      }
      ++r;
    }
  }
  int Kc = K < MAXDET ? K : MAXDET;
  for (int r2 = Kc + lane; r2 < MAXDET; r2 += 64) {
    float* o = out + ((size_t)b * MAXDET + r2) * 6;
    o[0] = 0.0f; o[1] = 0.0f; o[2] = 0.0f; o[3] = 0.0f; o[4] = 0.0f; o[5] = -1.0f;
  }
}

extern "C" void kernel_launch(void* const* d_in, const int* in_sizes, int n_in,
                              void* d_out, int out_size, void* d_ws, size_t ws_size,
                              hipStream_t stream) {
  const float* pred = (const float*)d_in[0];
  float* out = (float*)d_out;

  char* ws = (char*)d_ws;
  size_t off = 0;
  float*              scores = (float*)(ws + off);              off += (size_t)BB * NN * 4;
  uint8_t*            cls    = (uint8_t*)(ws + off);            off += (size_t)BB * NN;
  off = (off + 255) & ~(size_t)255;
  // contiguous zero-region: hist, gcnt, done, done2
  unsigned int*       hist   = (unsigned int*)(ws + off);       off += (size_t)BB * NBIN * 4;
  unsigned int*       gcnt   = (unsigned int*)(ws + off);       off += (size_t)BB * NBIN * 4;
  unsigned int*       done   = (unsigned int*)(ws + off);       off += (size_t)BB * 4;
  unsigned int*       done2  = (unsigned int*)(ws + off);       off += (size_t)BB * 4;
  const size_t zbytes = (size_t)BB * NBIN * 4 * 2 + (size_t)BB * 4 * 2;
  unsigned long long* gskey  = (unsigned long long*)(ws + off); off += (size_t)BB * SORTN * 8;
  float*              gtops  = (float*)(ws + off);              off += (size_t)BB * TK * 4;
  fvec4*              gbox   = (fvec4*)(ws + off);              off += (size_t)BB * TK * 16;
  int*                gcls   = (int*)(ws + off);                off += (size_t)BB * TK * 4;
  int*                keep   = (int*)(ws + off);                off += (size_t)BB * TK * 4;
  (void)ws_size; (void)in_sizes; (void)n_in; (void)out_size;

  hipMemsetAsync(hist, 0, zbytes, stream);
  score_kernel<<<dim3((NN + SROWS - 1) / SROWS, BB), 128, 0, stream>>>(pred, scores, cls, hist);
  scatter_emit_kernel<<<dim3(SCB, BB), 1024, 0, stream>>>(pred, cls, scores, hist, gcnt, done,
                                                          gskey, gtops, gbox, gcls, keep);
  nms_out_kernel<<<dim3(NCLS, BB), 64, 0, stream>>>(gtops, gbox, gcls, done2, keep, out);
}

// Round 12
// 245.328 us; speedup vs baseline: 1.8127x; 1.8127x over previous
//
#include <hip/hip_runtime.h>
#include <stdint.h>

#pragma clang fp contract(off)

#define BB 16
#define NN 25200
#define ROW 85
#define NCLS 80
#define TK 2048
#define SORTN 4096
#define NBIN 4096
#define MAXDET 1000
#define CONF 0.25f
#define IOUT 0.45f
#define SROWS 64
#define STH 0x3E800000u
#define MCAP 256

typedef float fvec4 __attribute__((ext_vector_type(4)));

#define AS1 __attribute__((address_space(1)))
#define AS3 __attribute__((address_space(3)))

// ---------------- K1: coalesced LDS staging + scores + argmax + global histogram ----------------
__global__ __launch_bounds__(128) void score_kernel(const float* __restrict__ pred,
                                                    float* __restrict__ scores,
                                                    uint8_t* __restrict__ cls,
                                                    unsigned int* __restrict__ hist) {
  __shared__ __align__(16) float srow[SROWS * ROW];  // 21760 B
  const int tile = blockIdx.x;
  const int b = blockIdx.y;
  const int tid = threadIdx.x;
  const int lane = tid & 63;
  const int row0 = tile * SROWS;
  int nrows = NN - row0;
  if (nrows > SROWS) nrows = SROWS;
  const char* gsrc = (const char*)(pred + ((size_t)b * NN + row0) * ROW);
  const int nbytes = nrows * ROW * 4;
  for (int off = tid * 16; off < nbytes; off += 128 * 16) {
    __builtin_amdgcn_global_load_lds((AS1 void*)(gsrc + off),
                                     (AS3 void*)((char*)srow + (off - lane * 16)),
                                     16, 0, 0);
  }
  __builtin_amdgcn_s_waitcnt(0);
  __syncthreads();
  if (tid < nrows) {
    const int n = row0 + tid;
    const float* r = srow + tid * ROW;   // stride 85 dwords -> 2-way bank alias (free)
    float obj = r[4];
    float best = r[5];
    int bid = 0;
#pragma unroll
    for (int c = 1; c < NCLS; ++c) {
      float p = r[5 + c];
      if (p > best) { best = p; bid = c; }   // strict > keeps first max (tie rule)
    }
    float score = obj * best;
    bool valid = (obj > CONF) && (score > CONF);
    float sout = valid ? score : 0.0f;
    scores[(size_t)b * NN + n] = sout;
    cls[(size_t)b * NN + n] = (uint8_t)bid;
    if (valid) {
      unsigned int u = __float_as_uint(sout);        // in (0x3E800000, 0x3F800000)
      unsigned int bin = (u - (STH + 1u)) >> 12;
      if (bin > NBIN - 1) bin = NBIN - 1;
      atomicAdd(&hist[(size_t)b * NBIN + bin], 1u);
    }
  }
}

// ---- 1024-thread per-block suffix scan over descending bins (R6 phase-2, proven) ----
// Fills soff[NBIN] (exclusive count of strictly-higher bins), *sPP = pivot, *sTT = total above+at pivot.
__device__ __forceinline__ void suffix_scan_1024(const unsigned int* __restrict__ h,
                                                 unsigned int* soff, int* swsum,
                                                 int* sPP, int* sTT,
                                                 int t, int w, int lane) {
  int loc[4];
  int ssum = 0;
#pragma unroll
  for (int k = 0; k < 4; ++k) {
    loc[k] = (int)h[NBIN - 1 - (4 * t + k)];
    ssum += loc[k];
  }
  int v = ssum;
  for (int o = 1; o < 64; o <<= 1) { int uu = __shfl_up(v, o); if (lane >= o) v += uu; }
  if (lane == 63) swsum[w] = v;
  if (t == 0) *sPP = -1;
  __syncthreads();
  if (w == 0) {
    int x = (lane < 16) ? swsum[lane] : 0;
    for (int o = 1; o < 16; o <<= 1) { int uu = __shfl_up(x, o); if (lane >= o) x += uu; }
    if (lane < 16) swsum[lane] = x;   // inclusive wave sums
  }
  __syncthreads();
  const int total = swsum[15];
  int run = (w ? swsum[w - 1] : 0) + (v - ssum);
#pragma unroll
  for (int k = 0; k < 4; ++k) {
    int bin = NBIN - 1 - (4 * t + k);
    soff[bin] = (unsigned int)run;
    if (run < TK && run + loc[k] >= TK) { *sPP = bin; *sTT = run + loc[k]; }  // unique bin
    run += loc[k];
  }
  __syncthreads();
  if (t == 0 && *sPP < 0) { *sPP = 0; *sTT = total; }  // total < TK (never with this data)
  __syncthreads();
}

// ---------------- K2: scatter to exact bin segments (per-block recomputed scan) ----------------
__global__ __launch_bounds__(1024) void scatter_kernel(const float* __restrict__ scores,
                                                       const unsigned int* __restrict__ hist,
                                                       unsigned int* __restrict__ gcnt,
                                                       unsigned long long* __restrict__ gskey) {
  const int b = blockIdx.y;
  const int t = threadIdx.x;
  const int w = t >> 6, lane = t & 63;
  __shared__ unsigned int soff[NBIN];   // 16 KB
  __shared__ int swsum[16];
  __shared__ int sP, sT;
  suffix_scan_1024(hist + (size_t)b * NBIN, soff, swsum, &sP, &sT, t, w, lane);
  const int P = sP;
  const int n = blockIdx.x * 1024 + t;
  if (n >= NN) return;
  unsigned int u = __float_as_uint(scores[(size_t)b * NN + n]);
  if (u > STH) {
    unsigned int bin = (u - (STH + 1u)) >> 12;
    if (bin > NBIN - 1) bin = NBIN - 1;
    if ((int)bin >= P) {
      unsigned int pos = soff[bin] + atomicAdd(&gcnt[(size_t)b * NBIN + bin], 1u);
      if (pos < SORTN)
        gskey[(size_t)b * SORTN + pos] = ((unsigned long long)u << 32) | (unsigned int)(~n);
    }
  }
}

// ---------------- K3: wide rank-by-count emit (per-block recomputed scan) ----------------
// Also zeroes keep[] for pad slots -> downstream needs no gtot guard (full keep coverage:
// slot < npos has a real class -> some nms block writes it; slot >= npos -> pad writes 0).
__global__ __launch_bounds__(1024) void emit_kernel(const float* __restrict__ pred,
                                                    const uint8_t* __restrict__ cls,
                                                    const unsigned int* __restrict__ hist,
                                                    const unsigned long long* __restrict__ gskey,
                                                    float* __restrict__ gtops,
                                                    fvec4* __restrict__ gbox,
                                                    int* __restrict__ gcls,
                                                    int* __restrict__ keep) {
  const int b = blockIdx.y;
  const int t = threadIdx.x;
  const int w = t >> 6, lane = t & 63;
  __shared__ unsigned int soff[NBIN];   // 16 KB
  __shared__ int swsum[16];
  __shared__ int sP, sT;
  const unsigned int* h = hist + (size_t)b * NBIN;
  suffix_scan_1024(h, soff, swsum, &sP, &sT, t, w, lane);
  const int tot = sT;
  const int used = tot < SORTN ? tot : SORTN;
  const int npos = tot < TK ? tot : TK;
  const int pp = blockIdx.x * 1024 + t;   // [0, SORTN)
  // pad job: fill [npos, TK) (no-op when tot >= TK)
  int ip = npos + pp;
  if (ip < TK) {
    gtops[(size_t)b * TK + ip] = 0.0f;
    gcls[(size_t)b * TK + ip] = 0xFFFF;
    keep[(size_t)b * TK + ip] = 0;
    fvec4 z; z[0] = 0.f; z[1] = 0.f; z[2] = 0.f; z[3] = 0.f;
    gbox[(size_t)b * TK + ip] = z;
  }
  if (pp < used) {
    unsigned long long k = gskey[(size_t)b * SORTN + pp];
    unsigned int u = (unsigned int)(k >> 32);
    unsigned int bin = (u - (STH + 1u)) >> 12;
    if (bin > NBIN - 1) bin = NBIN - 1;
    int base = (int)soff[bin];
    int cnt = (int)h[bin];               // scattered count == hist count (no drops: tot <= SORTN)
    if (base + cnt > used) cnt = used - base;   // safety
    const unsigned long long* seg = gskey + (size_t)b * SORTN + base;
    int rank = 0;
    for (int j = 0; j < cnt; ++j) rank += (seg[j] > k) ? 1 : 0;   // L2-resident, avg ~6
    int q = base + rank;                 // bijection over the segment (keys unique)
    if (q < npos) {
      int idx = (int)(~(unsigned int)k);
      gtops[(size_t)b * TK + q] = __uint_as_float(u);
      gcls[(size_t)b * TK + q] = (int)cls[(size_t)b * NN + idx];
      const float* rowp = pred + ((size_t)b * NN + idx) * ROW;
      float cx = rowp[0], cy = rowp[1], w2 = rowp[2], h2 = rowp[3];
      float hw = w2 * 0.5f, hh = h2 * 0.5f;
      fvec4 bb4;
      bb4[0] = cx - hw; bb4[1] = cy - hh; bb4[2] = cx + hw; bb4[3] = cy + hh;
      gbox[(size_t)b * TK + q] = bb4;
    }
  }
}

// ---------------- K4: greedy NMS, one wave per (batch, class) — member-staged, slim LDS ----
__global__ __launch_bounds__(64) void nms_kernel(const float* __restrict__ gtops,
                                                 const fvec4* __restrict__ gbox,
                                                 const int* __restrict__ gcls,
                                                 int* __restrict__ keep) {
  const int c = blockIdx.x;
  const int b = blockIdx.y;
  const int lane = threadIdx.x;
  __shared__ unsigned short spos[TK];                      // member -> global slot (4 KB)
  __shared__ float mx1[MCAP], my1[MCAP], mx2[MCAP], my2[MCAP];  // 4 KB
  __shared__ unsigned char skp[TK];                        // member keep flags (2 KB)

  int m = 0;
#pragma unroll 4
  for (int base = 0; base < TK; base += 64) {
    int j = base + lane;
    bool match = (gcls[(size_t)b * TK + j] == c);
    unsigned long long bal = __ballot(match);
    int mp = m + __popcll(bal & ((1ull << lane) - 1ull));
    if (match) {
      spos[mp] = (unsigned short)j;
      skp[mp] = (gtops[(size_t)b * TK + j] > 0.0f) ? 1 : 0;
      if (mp < MCAP) {
        fvec4 bx = gbox[(size_t)b * TK + j];
        mx1[mp] = bx[0]; my1[mp] = bx[1]; mx2[mp] = bx[2]; my2[mp] = bx[3];
      }
    }
    m += (int)__popcll(bal);
  }
  __syncthreads();

  // chunk-0 member box in registers (lane < 64 <= MCAP always staged)
  float b0x1 = 0.f, b0y1 = 0.f, b0x2 = 0.f, b0y2 = 0.f;
  if (lane < m) { b0x1 = mx1[lane]; b0y1 = my1[lane]; b0x2 = mx2[lane]; b0y2 = my2[lane]; }
  __syncthreads();

  for (int i = 0; i < m; ++i) {
    if (!skp[i]) continue;            // uniform broadcast read
    float ax1, ay1, ax2, ay2;
    if (i < 64) {
      ax1 = __shfl(b0x1, i); ay1 = __shfl(b0y1, i);
      ax2 = __shfl(b0x2, i); ay2 = __shfl(b0y2, i);
    } else if (i < MCAP) {
      ax1 = mx1[i]; ay1 = my1[i]; ax2 = mx2[i]; ay2 = my2[i];
    } else {                          // never in practice
      fvec4 bx = gbox[(size_t)b * TK + spos[i]];
      ax1 = bx[0]; ay1 = bx[1]; ax2 = bx[2]; ay2 = bx[3];
    }
    float aarea = (ax2 - ax1) * (ay2 - ay1);
    for (int q = 0; q * 64 < m; ++q) {
      int j = q * 64 + lane;          // each lane owns j == lane (mod 64): exclusive skp writes
      if (j > i && j < m && skp[j]) {
        float jx1, jy1, jx2, jy2;
        if (q == 0) { jx1 = b0x1; jy1 = b0y1; jx2 = b0x2; jy2 = b0y2; }
        else if (j < MCAP) { jx1 = mx1[j]; jy1 = my1[j]; jx2 = mx2[j]; jy2 = my2[j]; }
        else { fvec4 bx = gbox[(size_t)b * TK + spos[j]];
               jx1 = bx[0]; jy1 = bx[1]; jx2 = bx[2]; jy2 = bx[3]; }
        float ltx = fmaxf(ax1, jx1), lty = fmaxf(ay1, jy1);
        float rbx = fminf(ax2, jx2), rby = fminf(ay2, jy2);
        float iw = fmaxf(rbx - ltx, 0.0f);
        float ih = fmaxf(rby - lty, 0.0f);
        float inter = iw * ih;
        float barea = (jx2 - jx1) * (jy2 - jy1);
        float iou = inter / (aarea + barea - inter + 1e-7f);
        if (iou > IOUT) skp[j] = 0;
      }
    }
  }
  __syncthreads();

  for (int i = lane; i < m; i += 64) {
    keep[(size_t)b * TK + spos[i]] = skp[i];
  }
}

// ---------------- K5: compact first 1000 kept + padding (shfl scan; keep fully covered) ----------------
__global__ __launch_bounds__(256) void out_kernel(const float* __restrict__ gtops,
                                                  const fvec4* __restrict__ gbox,
                                                  const int* __restrict__ gcls,
                                                  const int* __restrict__ keep,
                                                  float* __restrict__ out) {
  int b = blockIdx.x;
  int t = threadIdx.x;
  int w = t >> 6, lane = t & 63;
  __shared__ int sw4[4];
  const int CH = TK / 256;  // 8
  int base = t * CH;
  int kp[CH];
  int cnt = 0;
  for (int k = 0; k < CH; ++k) {
    kp[k] = keep[(size_t)b * TK + base + k];   // pad slots hold 0 (written by emit)
    cnt += kp[k];
  }
  int v = cnt;
  for (int o = 1; o < 64; o <<= 1) { int u = __shfl_up(v, o); if (lane >= o) v += u; }
  if (lane == 63) sw4[w] = v;
  __syncthreads();
  int wbase = 0;
  for (int i = 0; i < w; ++i) wbase += sw4[i];
  int K = sw4[0] + sw4[1] + sw4[2] + sw4[3];
  int r = wbase + v - cnt;
  for (int k = 0; k < CH; ++k) {
    if (kp[k]) {
      if (r < MAXDET) {
        int j = base + k;
        float* o = out + ((size_t)b * MAXDET + r) * 6;
        fvec4 bx = gbox[(size_t)b * TK + j];
        o[0] = bx[0]; o[1] = bx[1]; o[2] = bx[2]; o[3] = bx[3];
        o[4] = gtops[(size_t)b * TK + j];
        o[5] = (float)gcls[(size_t)b * TK + j];
      }
      ++r;
    }
  }
  int Kc = K < MAXDET ? K : MAXDET;
  for (int r2 = Kc + t; r2 < MAXDET; r2 += 256) {
    float* o = out + ((size_t)b * MAXDET + r2) * 6;
    o[0] = 0.0f; o[1] = 0.0f; o[2] = 0.0f; o[3] = 0.0f; o[4] = 0.0f; o[5] = -1.0f;
  }
}

extern "C" void kernel_launch(void* const* d_in, const int* in_sizes, int n_in,
                              void* d_out, int out_size, void* d_ws, size_t ws_size,
                              hipStream_t stream) {
  const float* pred = (const float*)d_in[0];
  float* out = (float*)d_out;

  char* ws = (char*)d_ws;
  size_t off = 0;
  float*              scores = (float*)(ws + off);              off += (size_t)BB * NN * 4;
  uint8_t*            cls    = (uint8_t*)(ws + off);            off += (size_t)BB * NN;
  off = (off + 255) & ~(size_t)255;
  unsigned int*       hist   = (unsigned int*)(ws + off);       off += (size_t)BB * NBIN * 4;
  unsigned int*       gcnt   = (unsigned int*)(ws + off);       off += (size_t)BB * NBIN * 4;
  unsigned long long* gskey  = (unsigned long long*)(ws + off); off += (size_t)BB * SORTN * 8;
  float*              gtops  = (float*)(ws + off);              off += (size_t)BB * TK * 4;
  fvec4*              gbox   = (fvec4*)(ws + off);              off += (size_t)BB * TK * 16;
  int*                gcls   = (int*)(ws + off);                off += (size_t)BB * TK * 4;
  int*                keep   = (int*)(ws + off);                off += (size_t)BB * TK * 4;
  (void)ws_size; (void)in_sizes; (void)n_in; (void)out_size;

  // one memset clears hist AND gcnt (adjacent)
  hipMemsetAsync(hist, 0, (size_t)BB * NBIN * 4 * 2, stream);
  score_kernel<<<dim3((NN + SROWS - 1) / SROWS, BB), 128, 0, stream>>>(pred, scores, cls, hist);
  scatter_kernel<<<dim3((NN + 1023) / 1024, BB), 1024, 0, stream>>>(scores, hist, gcnt, gskey);
  emit_kernel<<<dim3(SORTN / 1024, BB), 1024, 0, stream>>>(pred, cls, hist, gskey,
                                                           gtops, gbox, gcls, keep);
  nms_kernel<<<dim3(NCLS, BB), 64, 0, stream>>>(gtops, gbox, gcls, keep);
  out_kernel<<<BB, 256, 0, stream>>>(gtops, gbox, gcls, keep, out);
}